// Round 2
// baseline (160.757 us; speedup 1.0000x reference)
//
#include <hip/hip_runtime.h>
#include <hip/hip_bf16.h>

typedef float f32x4 __attribute__((ext_vector_type(4)));
typedef __bf16 bf16x8 __attribute__((ext_vector_type(8)));

// ---------------------------------------------------------------------------
// GEMM1: h1(256x128) = x(256x256) @ w1(128x256)^T + b1
// ---------------------------------------------------------------------------
__global__ __launch_bounds__(128) void gemm1_k(const float* __restrict__ x,
                                               const float* __restrict__ w1,
                                               const float* __restrict__ b1,
                                               float* __restrict__ h1) {
    __shared__ float xs[256];
    const int m = blockIdx.x, t = threadIdx.x;
    xs[t] = x[m * 256 + t];
    xs[t + 128] = x[m * 256 + 128 + t];
    __syncthreads();
    float acc = b1[t];
    const float4* wr = (const float4*)(w1 + t * 256);
#pragma unroll 8
    for (int k4 = 0; k4 < 64; ++k4) {
        float4 w = wr[k4];
        acc += xs[k4 * 4 + 0] * w.x + xs[k4 * 4 + 1] * w.y +
               xs[k4 * 4 + 2] * w.z + xs[k4 * 4 + 3] * w.w;
    }
    h1[m * 128 + t] = acc;
}

// ---------------------------------------------------------------------------
// GEMM2: h2(256x4096) = h1(256x128) @ w2(4096x128)^T + b2
// grid (64 nb, 4 mb), 256 threads. Tiles 64x64, K=128.
// ---------------------------------------------------------------------------
__global__ __launch_bounds__(256) void gemm2_k(const float* __restrict__ h1,
                                               const float* __restrict__ w2,
                                               const float* __restrict__ b2,
                                               float* __restrict__ h2) {
    __shared__ float As[64][129];
    __shared__ float Bs[64][129];
    const int nb = blockIdx.x, mb = blockIdx.y, t = threadIdx.x;
#pragma unroll
    for (int i = 0; i < 8; ++i) {
        int idx = i * 256 + t;
        int row = idx >> 5, c4 = (idx & 31) * 4;
        float4 a = *(const float4*)(h1 + (mb * 64 + row) * 128 + c4);
        As[row][c4 + 0] = a.x; As[row][c4 + 1] = a.y;
        As[row][c4 + 2] = a.z; As[row][c4 + 3] = a.w;
        float4 bv = *(const float4*)(w2 + (nb * 64 + row) * 128 + c4);
        Bs[row][c4 + 0] = bv.x; Bs[row][c4 + 1] = bv.y;
        Bs[row][c4 + 2] = bv.z; Bs[row][c4 + 3] = bv.w;
    }
    __syncthreads();
    const int tx = t & 15, ty = t >> 4;
    float acc[4][4] = {};
#pragma unroll 4
    for (int k = 0; k < 128; ++k) {
        float a[4], b[4];
#pragma unroll
        for (int i = 0; i < 4; ++i) a[i] = As[ty * 4 + i][k];
#pragma unroll
        for (int j = 0; j < 4; ++j) b[j] = Bs[tx * 4 + j][k];
#pragma unroll
        for (int i = 0; i < 4; ++i)
#pragma unroll
            for (int j = 0; j < 4; ++j) acc[i][j] += a[i] * b[j];
    }
#pragma unroll
    for (int i = 0; i < 4; ++i)
#pragma unroll
        for (int j = 0; j < 4; ++j) {
            int n = nb * 64 + tx * 4 + j;
            h2[(mb * 64 + ty * 4 + i) * 4096 + n] = acc[i][j] + b2[n];
        }
}

// ---------------------------------------------------------------------------
// GEMM3: h3(256x16384) = h2(256x4096) @ w3(16384x4096)^T + b3   (bf16 MFMA)
// grid 256 (n-blocks of 64), 512 threads (8 waves, 4Mx2N wave grid).
// BM=256 (full M), BN=64, BK=64; double-buffered LDS; fp32->bf16 on staging.
// LDS map: A tiles at [cur*32768], W tiles at [65536 + cur*8192].
// ---------------------------------------------------------------------------
__device__ __forceinline__ void g3_load(const float* __restrict__ A,
                                        const float* __restrict__ W,
                                        int n0, int k0, int tid,
                                        float4 (&ar)[4][2], float4 (&wr)[2]) {
    const int kb = tid & 7, mrow = tid >> 3;
#pragma unroll
    for (int i = 0; i < 4; ++i) {
        const float* p = A + (i * 64 + mrow) * 4096 + k0 + kb * 8;
        ar[i][0] = *(const float4*)p;
        ar[i][1] = *(const float4*)(p + 4);
    }
    const float* q = W + (n0 + mrow) * 4096 + k0 + kb * 8;
    wr[0] = *(const float4*)q;
    wr[1] = *(const float4*)(q + 4);
}

__device__ __forceinline__ bf16x8 pack8(const float4& lo, const float4& hi) {
    bf16x8 p;
    p[0] = (__bf16)lo.x; p[1] = (__bf16)lo.y; p[2] = (__bf16)lo.z; p[3] = (__bf16)lo.w;
    p[4] = (__bf16)hi.x; p[5] = (__bf16)hi.y; p[6] = (__bf16)hi.z; p[7] = (__bf16)hi.w;
    return p;
}

__device__ __forceinline__ void g3_store(char* Ab, char* Wb, int tid,
                                         const float4 (&ar)[4][2],
                                         const float4 (&wr)[2]) {
    const int kb = tid & 7, mrow = tid >> 3;
#pragma unroll
    for (int i = 0; i < 4; ++i) {
        int m = i * 64 + mrow;
        *(bf16x8*)(Ab + ((m * 128 + kb * 16) ^ ((m & 7) << 4))) = pack8(ar[i][0], ar[i][1]);
    }
    *(bf16x8*)(Wb + ((mrow * 128 + kb * 16) ^ ((mrow & 7) << 4))) = pack8(wr[0], wr[1]);
}

__global__ __launch_bounds__(512, 1) void gemm3_k(const float* __restrict__ A,
                                                  const float* __restrict__ W,
                                                  const float* __restrict__ bias,
                                                  float* __restrict__ C) {
    __shared__ __align__(16) char lds[81920];
    const int tid = threadIdx.x;
    const int n0 = blockIdx.x * 64;

    float4 ar[4][2];
    float4 wr[2];
    g3_load(A, W, n0, 0, tid, ar, wr);
    g3_store(lds, lds + 65536, tid, ar, wr);
    __syncthreads();

    const int lane = tid & 63, wid = tid >> 6;
    const int lr = lane & 15, lq = lane >> 4;
    const int wm = wid >> 1, wn = wid & 1;

    f32x4 acc[4][2];
    const f32x4 zero = {0.f, 0.f, 0.f, 0.f};
#pragma unroll
    for (int mi = 0; mi < 4; ++mi)
#pragma unroll
        for (int ni = 0; ni < 2; ++ni) acc[mi][ni] = zero;

    for (int t = 0; t < 64; ++t) {
        const int cur = t & 1;
        if (t < 63) g3_load(A, W, n0, (t + 1) * 64, tid, ar, wr);
        const char* Ac = lds + cur * 32768;
        const char* Wc = lds + 65536 + cur * 8192;
#pragma unroll
        for (int kk = 0; kk < 2; ++kk) {
            const int kb = kk * 4 + lq;
            bf16x8 af[4], bfv[2];
#pragma unroll
            for (int mi = 0; mi < 4; ++mi) {
                int m = wm * 64 + mi * 16 + lr;
                af[mi] = *(const bf16x8*)(Ac + ((m * 128 + kb * 16) ^ ((m & 7) << 4)));
            }
#pragma unroll
            for (int ni = 0; ni < 2; ++ni) {
                int n = wn * 32 + ni * 16 + lr;
                bfv[ni] = *(const bf16x8*)(Wc + ((n * 128 + kb * 16) ^ ((n & 7) << 4)));
            }
#pragma unroll
            for (int mi = 0; mi < 4; ++mi)
#pragma unroll
                for (int ni = 0; ni < 2; ++ni)
                    acc[mi][ni] = __builtin_amdgcn_mfma_f32_16x16x32_bf16(
                        af[mi], bfv[ni], acc[mi][ni], 0, 0, 0);
        }
        __syncthreads();
        if (t < 63)
            g3_store(lds + (cur ^ 1) * 32768, lds + 65536 + (cur ^ 1) * 8192,
                     tid, ar, wr);
        __syncthreads();
    }

    float bv[2];
#pragma unroll
    for (int ni = 0; ni < 2; ++ni) bv[ni] = bias[n0 + wn * 32 + ni * 16 + lr];
#pragma unroll
    for (int mi = 0; mi < 4; ++mi)
#pragma unroll
        for (int ni = 0; ni < 2; ++ni) {
            const int n = n0 + wn * 32 + ni * 16 + lr;
#pragma unroll
            for (int r = 0; r < 4; ++r) {
                int m = wm * 64 + mi * 16 + lq * 4 + r;
                C[m * 16384 + n] = acc[mi][ni][r] + bv[ni];
            }
        }
}

// ---------------------------------------------------------------------------
// Fused conv x5 (bf16 MFMA) + square + Sinkhorn. One block per batch element.
// LDS: xtA (34816) | xtB (31488) | wl (36864) | S 64x65 f32 (16640)
// XT layout: [col l][ci], bf16, byte = (l*CIN*2 + (ci>>3)*16 + (ci&7)*2) ^ ((l&7)<<4)
// Wl layout: [tap][cib(4)][co][8ci] 16B blocks
// ---------------------------------------------------------------------------
template <int CIN, int COUT, int DIL, int MT, int NT>
__device__ __forceinline__ void conv_core(const char* xt, char* wl,
                                          const float* __restrict__ w,
                                          f32x4 (&acc)[MT][NT], int tid) {
    constexpr int RB = CIN * 2;
    const int lane = tid & 63, wid = tid >> 6;
    const int lr = lane & 15, lq = lane >> 4;
    const int cobase = wid * (COUT / 4);
    const f32x4 zero = {0.f, 0.f, 0.f, 0.f};
#pragma unroll
    for (int mi = 0; mi < MT; ++mi)
#pragma unroll
        for (int ni = 0; ni < NT; ++ni) acc[mi][ni] = zero;

    for (int cic = 0; cic < CIN / 32; ++cic) {
        // stage weight chunk: w[co][ci0..ci0+7][tap] -> Wl[tap][cib][co]
        for (int idx = tid; idx < COUT * 4; idx += 256) {
            int co = idx >> 2, cib = idx & 3, ci0 = cic * 32 + cib * 8;
            const float* src = w + co * (CIN * 3) + ci0 * 3;
            float v[24];
#pragma unroll
            for (int u = 0; u < 6; ++u) {
                float4 f = *(const float4*)(src + u * 4);
                v[u * 4 + 0] = f.x; v[u * 4 + 1] = f.y;
                v[u * 4 + 2] = f.z; v[u * 4 + 3] = f.w;
            }
#pragma unroll
            for (int tp = 0; tp < 3; ++tp) {
                bf16x8 pk;
#pragma unroll
                for (int j = 0; j < 8; ++j) pk[j] = (__bf16)v[j * 3 + tp];
                *(bf16x8*)(wl + ((tp * 4 + cib) * COUT + co) * 16) = pk;
            }
        }
        __syncthreads();
#pragma unroll
        for (int tp = 0; tp < 3; ++tp) {
            bf16x8 af[MT];
#pragma unroll
            for (int mi = 0; mi < MT; ++mi)
                af[mi] = *(const bf16x8*)(wl + ((tp * 4 + lq) * COUT + cobase + mi * 16 + lr) * 16);
            bf16x8 bfr[NT];
#pragma unroll
            for (int ni = 0; ni < NT; ++ni) {
                int colX = ni * 16 + lr + tp * DIL;
                bfr[ni] = *(const bf16x8*)(xt + ((colX * RB + (cic * 4 + lq) * 16) ^ ((colX & 7) << 4)));
            }
#pragma unroll
            for (int mi = 0; mi < MT; ++mi)
#pragma unroll
                for (int ni = 0; ni < NT; ++ni)
                    acc[mi][ni] = __builtin_amdgcn_mfma_f32_16x16x32_bf16(
                        af[mi], bfr[ni], acc[mi][ni], 0, 0, 0);
        }
        __syncthreads();
    }
}

template <int COUT, int LOUT, int MT, int NT>
__device__ __forceinline__ void write_xt(char* xt_out, const f32x4 (&acc)[MT][NT],
                                         const float* __restrict__ bias, int tid) {
    constexpr int RBO = COUT * 2;
    const int lane = tid & 63, wid = tid >> 6;
    const int lr = lane & 15, lq = lane >> 4;
    const int cobase = wid * (COUT / 4);
#pragma unroll
    for (int mi = 0; mi < MT; ++mi)
#pragma unroll
        for (int ni = 0; ni < NT; ++ni) {
            int l = ni * 16 + lr;
            if (l < LOUT) {
#pragma unroll
                for (int r = 0; r < 4; ++r) {
                    int co = cobase + mi * 16 + lq * 4 + r;
                    float y = acc[mi][ni][r] + bias[co];
                    int byte = (l * RBO + ((co >> 3) << 4) + (co & 7) * 2) ^ ((l & 7) << 4);
                    *(__bf16*)(xt_out + byte) = (__bf16)y;
                }
            }
        }
}

__global__ __launch_bounds__(256, 1) void convsink_k(
    const float* __restrict__ h3,
    const float* __restrict__ cw1, const float* __restrict__ cb1,
    const float* __restrict__ cw2, const float* __restrict__ cb2,
    const float* __restrict__ cw3, const float* __restrict__ cb3,
    const float* __restrict__ cw4, const float* __restrict__ cb4,
    const float* __restrict__ cw5, const float* __restrict__ cb5,
    float* __restrict__ out) {
    __shared__ __align__(16) char lds[34816 + 31488 + 36864 + 16640];
    char* xtA = lds;
    char* xtB = lds + 34816;
    char* wl = lds + 34816 + 31488;
    float* S = (float*)(lds + 34816 + 31488 + 36864);

    const int b = blockIdx.x, tid = threadIdx.x;
    const float* src = h3 + b * 16384;

    // stage XT1[l][ci] (128 cols x 128 ci), lane<->l coalesced global reads
#pragma unroll
    for (int i = 0; i < 8; ++i) {
        int idx = i * 256 + tid;
        int l = idx & 127, cib = idx >> 7;
        bf16x8 p;
#pragma unroll
        for (int j = 0; j < 8; ++j) p[j] = (__bf16)src[(cib * 8 + j) * 128 + l];
        *(bf16x8*)(xtA + ((l * 256 + cib * 16) ^ ((l & 7) << 4))) = p;
    }
    __syncthreads();

    {
        f32x4 acc[3][5];
        conv_core<128, 192, 28, 3, 5>(xtA, wl, cw1, acc, tid);
        write_xt<192, 72, 3, 5>(xtB, acc, cb1, tid);
    }
    __syncthreads();
    {
        f32x4 acc[2][5];
        conv_core<192, 128, 1, 2, 5>(xtB, wl, cw2, acc, tid);
        write_xt<128, 70, 2, 5>(xtA, acc, cb2, tid);
    }
    __syncthreads();
    {
        f32x4 acc[1][5];
        conv_core<128, 64, 1, 1, 5>(xtA, wl, cw3, acc, tid);
        write_xt<64, 68, 1, 5>(xtB, acc, cb3, tid);
    }
    __syncthreads();
    {
        f32x4 acc[1][5];
        conv_core<64, 64, 1, 1, 5>(xtB, wl, cw4, acc, tid);
        write_xt<64, 66, 1, 5>(xtA, acc, cb4, tid);
    }
    __syncthreads();
    {
        f32x4 acc[1][4];
        conv_core<64, 64, 1, 1, 4>(xtA, wl, cw5, acc, tid);
        const int lane = tid & 63, wid = tid >> 6;
        const int lr = lane & 15, lq = lane >> 4;
        const int cobase = wid * 16;
#pragma unroll
        for (int ni = 0; ni < 4; ++ni) {
            int l = ni * 16 + lr;
#pragma unroll
            for (int r = 0; r < 4; ++r) {
                int co = cobase + lq * 4 + r;
                float y = acc[0][ni][r] + cb5[co];
                S[co * 65 + l] = y * y + 0.001f;
            }
        }
    }
    __syncthreads();

    // Sinkhorn: 10x { row-normalize (over l), col-normalize (over co) }
    const int q = tid & 3, rid = tid >> 2;
    for (int it = 0; it < 10; ++it) {
        float p = 0.f;
#pragma unroll
        for (int j = 0; j < 16; ++j) p += S[rid * 65 + q * 16 + j];
        p += __shfl_xor(p, 1);
        p += __shfl_xor(p, 2);
        float inv = 1.0f / p;
#pragma unroll
        for (int j = 0; j < 16; ++j) S[rid * 65 + q * 16 + j] *= inv;
        __syncthreads();
        float c = 0.f;
#pragma unroll
        for (int i = 0; i < 16; ++i) c += S[(q * 16 + i) * 65 + rid];
        c += __shfl_xor(c, 1);
        c += __shfl_xor(c, 2);
        float invc = 1.0f / c;
#pragma unroll
        for (int i = 0; i < 16; ++i) S[(q * 16 + i) * 65 + rid] *= invc;
        __syncthreads();
    }

#pragma unroll
    for (int i = 0; i < 16; ++i) {
        int idx = i * 256 + tid;
        out[b * 4096 + idx] = S[(idx >> 6) * 65 + (idx & 63)];
    }
}

// ---------------------------------------------------------------------------
extern "C" void kernel_launch(void* const* d_in, const int* in_sizes, int n_in,
                              void* d_out, int out_size, void* d_ws, size_t ws_size,
                              hipStream_t stream) {
    const float* x = (const float*)d_in[0];
    const float* w1 = (const float*)d_in[1];
    const float* b1 = (const float*)d_in[2];
    const float* w2 = (const float*)d_in[3];
    const float* b2 = (const float*)d_in[4];
    const float* w3 = (const float*)d_in[5];
    const float* b3 = (const float*)d_in[6];
    const float* cw1 = (const float*)d_in[7];
    const float* cb1 = (const float*)d_in[8];
    const float* cw2 = (const float*)d_in[9];
    const float* cb2 = (const float*)d_in[10];
    const float* cw3 = (const float*)d_in[11];
    const float* cb3 = (const float*)d_in[12];
    const float* cw4 = (const float*)d_in[13];
    const float* cb4 = (const float*)d_in[14];
    const float* cw5 = (const float*)d_in[15];
    const float* cb5 = (const float*)d_in[16];
    float* out = (float*)d_out;

    char* ws = (char*)d_ws;
    float* h1 = (float*)(ws);                      // 256*128*4   = 131072 B
    float* h2 = (float*)(ws + 131072);             // 256*4096*4  = 4194304 B
    float* h3 = (float*)(ws + 131072 + 4194304);   // 256*16384*4 = 16777216 B

    gemm1_k<<<256, 128, 0, stream>>>(x, w1, b1, h1);
    gemm2_k<<<dim3(64, 4), 256, 0, stream>>>(h1, w2, b2, h2);
    gemm3_k<<<256, 512, 0, stream>>>(h2, w3, b3, h3);
    convsink_k<<<256, 256, 0, stream>>>(h3, cw1, cb1, cw2, cb2, cw3, cb3,
                                        cw4, cb4, cw5, cb5, out);
}

// Round 3
// 150.114 us; speedup vs baseline: 1.0709x; 1.0709x over previous
//
#include <hip/hip_runtime.h>
#include <hip/hip_bf16.h>

typedef float f32x4 __attribute__((ext_vector_type(4)));
typedef __bf16 bf16x8 __attribute__((ext_vector_type(8)));

typedef __attribute__((address_space(1))) const unsigned int as1_uint;
typedef __attribute__((address_space(3))) unsigned int as3_uint;

// ---------------------------------------------------------------------------
// GEMM1: h1(256x128) = x(256x256) @ w1(128x256)^T + b1
// ---------------------------------------------------------------------------
__global__ __launch_bounds__(128) void gemm1_k(const float* __restrict__ x,
                                               const float* __restrict__ w1,
                                               const float* __restrict__ b1,
                                               float* __restrict__ h1) {
    __shared__ float xs[256];
    const int m = blockIdx.x, t = threadIdx.x;
    xs[t] = x[m * 256 + t];
    xs[t + 128] = x[m * 256 + 128 + t];
    __syncthreads();
    float acc = b1[t];
    const float4* wr = (const float4*)(w1 + t * 256);
#pragma unroll 8
    for (int k4 = 0; k4 < 64; ++k4) {
        float4 w = wr[k4];
        acc += xs[k4 * 4 + 0] * w.x + xs[k4 * 4 + 1] * w.y +
               xs[k4 * 4 + 2] * w.z + xs[k4 * 4 + 3] * w.w;
    }
    h1[m * 128 + t] = acc;
}

// ---------------------------------------------------------------------------
// GEMM2: h2b = bf16 pre-swizzled "LDS image" of h1 @ w2^T + b2.
// Image: 64 K-step tiles of 32KB; byte(m, n) =
//   (n>>6)*32768 + ((m*128 + ((n&63)>>3)*16) ^ ((m&7)<<4)) + (n&7)*2
// This is exactly the A-tile byte layout gemm3's MFMA fragments read.
// ---------------------------------------------------------------------------
__global__ __launch_bounds__(256) void gemm2_k(const float* __restrict__ h1,
                                               const float* __restrict__ w2,
                                               const float* __restrict__ b2,
                                               char* __restrict__ h2b) {
    __shared__ float As[64][129];
    __shared__ float Bs[64][129];
    const int nb = blockIdx.x, mb = blockIdx.y, t = threadIdx.x;
#pragma unroll
    for (int i = 0; i < 8; ++i) {
        int idx = i * 256 + t;
        int row = idx >> 5, c4 = (idx & 31) * 4;
        float4 a = *(const float4*)(h1 + (mb * 64 + row) * 128 + c4);
        As[row][c4 + 0] = a.x; As[row][c4 + 1] = a.y;
        As[row][c4 + 2] = a.z; As[row][c4 + 3] = a.w;
        float4 bv = *(const float4*)(w2 + (nb * 64 + row) * 128 + c4);
        Bs[row][c4 + 0] = bv.x; Bs[row][c4 + 1] = bv.y;
        Bs[row][c4 + 2] = bv.z; Bs[row][c4 + 3] = bv.w;
    }
    __syncthreads();
    const int tx = t & 15, ty = t >> 4;
    float acc[4][4] = {};
#pragma unroll 4
    for (int k = 0; k < 128; ++k) {
        float a[4], b[4];
#pragma unroll
        for (int i = 0; i < 4; ++i) a[i] = As[ty * 4 + i][k];
#pragma unroll
        for (int j = 0; j < 4; ++j) b[j] = Bs[tx * 4 + j][k];
#pragma unroll
        for (int i = 0; i < 4; ++i)
#pragma unroll
            for (int j = 0; j < 4; ++j) acc[i][j] += a[i] * b[j];
    }
#pragma unroll
    for (int i = 0; i < 4; ++i)
#pragma unroll
        for (int j = 0; j < 4; ++j) {
            int m = mb * 64 + ty * 4 + i;
            int n = nb * 64 + tx * 4 + j;
            float v = acc[i][j] + b2[n];
            int kb = n >> 6, r = n & 63;
            int byte = kb * 32768 + ((m * 128 + (r >> 3) * 16) ^ ((m & 7) << 4)) + (r & 7) * 2;
            *(__bf16*)(h2b + byte) = (__bf16)v;
        }
}

// ---------------------------------------------------------------------------
// GEMM3: h3(256x16384) = h2(256x4096) @ w3(16384x4096)^T + b3   (bf16 MFMA)
// grid 256 (n-blocks of 64), 512 threads (8 waves, 4Mx2N wave grid).
// A staged via global_load_lds (16B) from the pre-swizzled bf16 image h2b.
// W staged fp32 -> reg -> bf16 -> LDS (only 32B/thread/step).
// LDS: A dbuf 2x32768, W dbuf 2x8192 at +65536.
// ---------------------------------------------------------------------------
__global__ __launch_bounds__(512, 1) void gemm3_k(const char* __restrict__ Ab,
                                                  const float* __restrict__ W,
                                                  const float* __restrict__ bias,
                                                  float* __restrict__ C) {
    __shared__ __align__(16) char lds[81920];
    const int tid = threadIdx.x;
    const int n0 = blockIdx.x * 64;
    const int lane = tid & 63, wid = tid >> 6;
    const int mrow = tid >> 3, kb8 = tid & 7;

    // --- staging helpers ---
    // A: wave `wid` DMAs bytes [wid*4096 + i*1024 + lane*16] of the 32KB image.
    // LDS dest is wave-uniform base; HW adds lane*16. Global src is per-lane.
#define ISSUE_A(t, buf)                                                          \
    {                                                                            \
        const char* _s = Ab + (t) * 32768 + wid * 4096 + lane * 16;              \
        char* _d = lds + (buf) * 32768 + wid * 4096;                             \
        __builtin_amdgcn_global_load_lds((as1_uint*)(_s), (as3_uint*)(_d), 16, 0, 0);          \
        __builtin_amdgcn_global_load_lds((as1_uint*)(_s + 1024), (as3_uint*)(_d + 1024), 16, 0, 0); \
        __builtin_amdgcn_global_load_lds((as1_uint*)(_s + 2048), (as3_uint*)(_d + 2048), 16, 0, 0); \
        __builtin_amdgcn_global_load_lds((as1_uint*)(_s + 3072), (as3_uint*)(_d + 3072), 16, 0, 0); \
    }

    float4 w0, w1;
    auto loadW = [&](int t) {
        const float* q = W + (n0 + mrow) * 4096 + t * 64 + kb8 * 8;
        w0 = *(const float4*)q;
        w1 = *(const float4*)(q + 4);
    };
    auto storeW = [&](int buf) {
        bf16x8 p;
        p[0] = (__bf16)w0.x; p[1] = (__bf16)w0.y; p[2] = (__bf16)w0.z; p[3] = (__bf16)w0.w;
        p[4] = (__bf16)w1.x; p[5] = (__bf16)w1.y; p[6] = (__bf16)w1.z; p[7] = (__bf16)w1.w;
        *(bf16x8*)(lds + 65536 + buf * 8192 +
                   ((mrow * 128 + kb8 * 16) ^ ((mrow & 7) << 4))) = p;
    };

    // prologue: tile 0
    ISSUE_A(0, 0);
    loadW(0);
    __syncthreads();   // vmcnt drain: A(0) resident, w regs ready
    storeW(0);
    __syncthreads();   // W(0) visible

    const int lr = lane & 15, lq = lane >> 4;
    const int wm = wid >> 1, wn = wid & 1;

    f32x4 acc[4][2];
    const f32x4 zero = {0.f, 0.f, 0.f, 0.f};
#pragma unroll
    for (int mi = 0; mi < 4; ++mi)
#pragma unroll
        for (int ni = 0; ni < 2; ++ni) acc[mi][ni] = zero;

    for (int t = 0; t < 64; ++t) {
        const int cur = t & 1;
        if (t < 63) {
            ISSUE_A(t + 1, cur ^ 1);
            loadW(t + 1);
        }
        const char* Ac = lds + cur * 32768;
        const char* Wc = lds + 65536 + cur * 8192;
#pragma unroll
        for (int kk = 0; kk < 2; ++kk) {
            const int kb = kk * 4 + lq;
            bf16x8 af[4], bfv[2];
#pragma unroll
            for (int mi = 0; mi < 4; ++mi) {
                int m = wm * 64 + mi * 16 + lr;
                af[mi] = *(const bf16x8*)(Ac + ((m * 128 + kb * 16) ^ ((m & 7) << 4)));
            }
#pragma unroll
            for (int ni = 0; ni < 2; ++ni) {
                int n = wn * 32 + ni * 16 + lr;
                bfv[ni] = *(const bf16x8*)(Wc + ((n * 128 + kb * 16) ^ ((n & 7) << 4)));
            }
#pragma unroll
            for (int mi = 0; mi < 4; ++mi)
#pragma unroll
                for (int ni = 0; ni < 2; ++ni)
                    acc[mi][ni] = __builtin_amdgcn_mfma_f32_16x16x32_bf16(
                        af[mi], bfv[ni], acc[mi][ni], 0, 0, 0);
        }
        __syncthreads();   // reads of cur done; vmcnt drain -> A(t+1) resident
        if (t < 63) storeW(cur ^ 1);
        __syncthreads();   // W(t+1) visible
    }
#undef ISSUE_A

    float bv[2];
#pragma unroll
    for (int ni = 0; ni < 2; ++ni) bv[ni] = bias[n0 + wn * 32 + ni * 16 + lr];
#pragma unroll
    for (int mi = 0; mi < 4; ++mi)
#pragma unroll
        for (int ni = 0; ni < 2; ++ni) {
            const int n = n0 + wn * 32 + ni * 16 + lr;
#pragma unroll
            for (int r = 0; r < 4; ++r) {
                int m = wm * 64 + mi * 16 + lq * 4 + r;
                C[m * 16384 + n] = acc[mi][ni][r] + bv[ni];
            }
        }
}

// ---------------------------------------------------------------------------
// Fused conv x5 (bf16 MFMA) + square + Sinkhorn. One block per batch element.
// LDS: xtA (34816) | xtB (31488) | wl (36864) | S 64x65 f32 (16640)
// XT layout: [col l][ci], bf16, byte = (l*CIN*2 + (ci>>3)*16 + (ci&7)*2) ^ ((l&7)<<4)
// Wl layout: [tap][cib(4)][co][8ci] 16B blocks
// ---------------------------------------------------------------------------
template <int CIN, int COUT, int DIL, int MT, int NT>
__device__ __forceinline__ void conv_core(const char* xt, char* wl,
                                          const float* __restrict__ w,
                                          f32x4 (&acc)[MT][NT], int tid) {
    constexpr int RB = CIN * 2;
    const int lane = tid & 63, wid = tid >> 6;
    const int lr = lane & 15, lq = lane >> 4;
    const int cobase = wid * (COUT / 4);
    const f32x4 zero = {0.f, 0.f, 0.f, 0.f};
#pragma unroll
    for (int mi = 0; mi < MT; ++mi)
#pragma unroll
        for (int ni = 0; ni < NT; ++ni) acc[mi][ni] = zero;

    for (int cic = 0; cic < CIN / 32; ++cic) {
        // stage weight chunk: w[co][ci0..ci0+7][tap] -> Wl[tap][cib][co]
        for (int idx = tid; idx < COUT * 4; idx += 256) {
            int co = idx >> 2, cib = idx & 3, ci0 = cic * 32 + cib * 8;
            const float* src = w + co * (CIN * 3) + ci0 * 3;
            float v[24];
#pragma unroll
            for (int u = 0; u < 6; ++u) {
                float4 f = *(const float4*)(src + u * 4);
                v[u * 4 + 0] = f.x; v[u * 4 + 1] = f.y;
                v[u * 4 + 2] = f.z; v[u * 4 + 3] = f.w;
            }
#pragma unroll
            for (int tp = 0; tp < 3; ++tp) {
                bf16x8 pk;
#pragma unroll
                for (int j = 0; j < 8; ++j) pk[j] = (__bf16)v[j * 3 + tp];
                *(bf16x8*)(wl + ((tp * 4 + cib) * COUT + co) * 16) = pk;
            }
        }
        __syncthreads();
#pragma unroll
        for (int tp = 0; tp < 3; ++tp) {
            bf16x8 af[MT];
#pragma unroll
            for (int mi = 0; mi < MT; ++mi)
                af[mi] = *(const bf16x8*)(wl + ((tp * 4 + lq) * COUT + cobase + mi * 16 + lr) * 16);
            bf16x8 bfr[NT];
#pragma unroll
            for (int ni = 0; ni < NT; ++ni) {
                int colX = ni * 16 + lr + tp * DIL;
                bfr[ni] = *(const bf16x8*)(xt + ((colX * RB + (cic * 4 + lq) * 16) ^ ((colX & 7) << 4)));
            }
#pragma unroll
            for (int mi = 0; mi < MT; ++mi)
#pragma unroll
                for (int ni = 0; ni < NT; ++ni)
                    acc[mi][ni] = __builtin_amdgcn_mfma_f32_16x16x32_bf16(
                        af[mi], bfr[ni], acc[mi][ni], 0, 0, 0);
        }
        __syncthreads();
    }
}

template <int COUT, int LOUT, int MT, int NT>
__device__ __forceinline__ void write_xt(char* xt_out, const f32x4 (&acc)[MT][NT],
                                         const float* __restrict__ bias, int tid) {
    constexpr int RBO = COUT * 2;
    const int lane = tid & 63, wid = tid >> 6;
    const int lr = lane & 15, lq = lane >> 4;
    const int cobase = wid * (COUT / 4);
#pragma unroll
    for (int mi = 0; mi < MT; ++mi)
#pragma unroll
        for (int ni = 0; ni < NT; ++ni) {
            int l = ni * 16 + lr;
            if (l < LOUT) {
#pragma unroll
                for (int r = 0; r < 4; ++r) {
                    int co = cobase + mi * 16 + lq * 4 + r;
                    float y = acc[mi][ni][r] + bias[co];
                    int byte = (l * RBO + ((co >> 3) << 4) + (co & 7) * 2) ^ ((l & 7) << 4);
                    *(__bf16*)(xt_out + byte) = (__bf16)y;
                }
            }
        }
}

__global__ __launch_bounds__(256, 1) void convsink_k(
    const float* __restrict__ h3,
    const float* __restrict__ cw1, const float* __restrict__ cb1,
    const float* __restrict__ cw2, const float* __restrict__ cb2,
    const float* __restrict__ cw3, const float* __restrict__ cb3,
    const float* __restrict__ cw4, const float* __restrict__ cb4,
    const float* __restrict__ cw5, const float* __restrict__ cb5,
    float* __restrict__ out) {
    __shared__ __align__(16) char lds[34816 + 31488 + 36864 + 16640];
    char* xtA = lds;
    char* xtB = lds + 34816;
    char* wl = lds + 34816 + 31488;
    float* S = (float*)(lds + 34816 + 31488 + 36864);

    const int b = blockIdx.x, tid = threadIdx.x;
    const float* src = h3 + b * 16384;

    // stage XT1[l][ci] (128 cols x 128 ci), lane<->l coalesced global reads
#pragma unroll
    for (int i = 0; i < 8; ++i) {
        int idx = i * 256 + tid;
        int l = idx & 127, cib = idx >> 7;
        bf16x8 p;
#pragma unroll
        for (int j = 0; j < 8; ++j) p[j] = (__bf16)src[(cib * 8 + j) * 128 + l];
        *(bf16x8*)(xtA + ((l * 256 + cib * 16) ^ ((l & 7) << 4))) = p;
    }
    __syncthreads();

    {
        f32x4 acc[3][5];
        conv_core<128, 192, 28, 3, 5>(xtA, wl, cw1, acc, tid);
        write_xt<192, 72, 3, 5>(xtB, acc, cb1, tid);
    }
    __syncthreads();
    {
        f32x4 acc[2][5];
        conv_core<192, 128, 1, 2, 5>(xtB, wl, cw2, acc, tid);
        write_xt<128, 70, 2, 5>(xtA, acc, cb2, tid);
    }
    __syncthreads();
    {
        f32x4 acc[1][5];
        conv_core<128, 64, 1, 1, 5>(xtA, wl, cw3, acc, tid);
        write_xt<64, 68, 1, 5>(xtB, acc, cb3, tid);
    }
    __syncthreads();
    {
        f32x4 acc[1][5];
        conv_core<64, 64, 1, 1, 5>(xtB, wl, cw4, acc, tid);
        write_xt<64, 66, 1, 5>(xtA, acc, cb4, tid);
    }
    __syncthreads();
    {
        f32x4 acc[1][4];
        conv_core<64, 64, 1, 1, 4>(xtA, wl, cw5, acc, tid);
        const int lane = tid & 63, wid = tid >> 6;
        const int lr = lane & 15, lq = lane >> 4;
        const int cobase = wid * 16;
#pragma unroll
        for (int ni = 0; ni < 4; ++ni) {
            int l = ni * 16 + lr;
#pragma unroll
            for (int r = 0; r < 4; ++r) {
                int co = cobase + lq * 4 + r;
                float y = acc[0][ni][r] + cb5[co];
                S[co * 65 + l] = y * y + 0.001f;
            }
        }
    }
    __syncthreads();

    // Sinkhorn: 10x { row-normalize (over l), col-normalize (over co) }
    const int q = tid & 3, rid = tid >> 2;
    for (int it = 0; it < 10; ++it) {
        float p = 0.f;
#pragma unroll
        for (int j = 0; j < 16; ++j) p += S[rid * 65 + q * 16 + j];
        p += __shfl_xor(p, 1);
        p += __shfl_xor(p, 2);
        float inv = 1.0f / p;
#pragma unroll
        for (int j = 0; j < 16; ++j) S[rid * 65 + q * 16 + j] *= inv;
        __syncthreads();
        float c = 0.f;
#pragma unroll
        for (int i = 0; i < 16; ++i) c += S[(q * 16 + i) * 65 + rid];
        c += __shfl_xor(c, 1);
        c += __shfl_xor(c, 2);
        float invc = 1.0f / c;
#pragma unroll
        for (int i = 0; i < 16; ++i) S[(q * 16 + i) * 65 + rid] *= invc;
        __syncthreads();
    }

#pragma unroll
    for (int i = 0; i < 16; ++i) {
        int idx = i * 256 + tid;
        out[b * 4096 + idx] = S[(idx >> 6) * 65 + (idx & 63)];
    }
}

// ---------------------------------------------------------------------------
extern "C" void kernel_launch(void* const* d_in, const int* in_sizes, int n_in,
                              void* d_out, int out_size, void* d_ws, size_t ws_size,
                              hipStream_t stream) {
    const float* x = (const float*)d_in[0];
    const float* w1 = (const float*)d_in[1];
    const float* b1 = (const float*)d_in[2];
    const float* w2 = (const float*)d_in[3];
    const float* b2 = (const float*)d_in[4];
    const float* w3 = (const float*)d_in[5];
    const float* b3 = (const float*)d_in[6];
    const float* cw1 = (const float*)d_in[7];
    const float* cb1 = (const float*)d_in[8];
    const float* cw2 = (const float*)d_in[9];
    const float* cb2 = (const float*)d_in[10];
    const float* cw3 = (const float*)d_in[11];
    const float* cb3 = (const float*)d_in[12];
    const float* cw4 = (const float*)d_in[13];
    const float* cb4 = (const float*)d_in[14];
    const float* cw5 = (const float*)d_in[15];
    const float* cb5 = (const float*)d_in[16];
    float* out = (float*)d_out;

    char* ws = (char*)d_ws;
    float* h1 = (float*)(ws);                       // 256*128*4        = 131072 B
    char* h2b = ws + 131072;                        // bf16 image 2 MB  = 2097152 B
    float* h3 = (float*)(ws + 131072 + 2097152);    // 256*16384*4      = 16777216 B

    gemm1_k<<<256, 128, 0, stream>>>(x, w1, b1, h1);
    gemm2_k<<<dim3(64, 4), 256, 0, stream>>>(h1, w2, b2, h2b);
    gemm3_k<<<256, 512, 0, stream>>>(h2b, w3, b3, h3);
    convsink_k<<<256, 256, 0, stream>>>(h3, cw1, cb1, cw2, cb2, cw3, cb3,
                                        cw4, cb4, cw5, cb5, out);
}

// Round 4
// 144.230 us; speedup vs baseline: 1.1146x; 1.0408x over previous
//
#include <hip/hip_runtime.h>
#include <hip/hip_bf16.h>

typedef float f32x4 __attribute__((ext_vector_type(4)));
typedef __bf16 bf16x8 __attribute__((ext_vector_type(8)));

typedef __attribute__((address_space(1))) const unsigned int as1_uint;
typedef __attribute__((address_space(3))) unsigned int as3_uint;

// ---------------------------------------------------------------------------
// GEMM1: h1(256x128) = x(256x256) @ w1(128x256)^T + b1
// ---------------------------------------------------------------------------
__global__ __launch_bounds__(128) void gemm1_k(const float* __restrict__ x,
                                               const float* __restrict__ w1,
                                               const float* __restrict__ b1,
                                               float* __restrict__ h1) {
    __shared__ float xs[256];
    const int m = blockIdx.x, t = threadIdx.x;
    xs[t] = x[m * 256 + t];
    xs[t + 128] = x[m * 256 + 128 + t];
    __syncthreads();
    float acc = b1[t];
    const float4* wr = (const float4*)(w1 + t * 256);
#pragma unroll 8
    for (int k4 = 0; k4 < 64; ++k4) {
        float4 w = wr[k4];
        acc += xs[k4 * 4 + 0] * w.x + xs[k4 * 4 + 1] * w.y +
               xs[k4 * 4 + 2] * w.z + xs[k4 * 4 + 3] * w.w;
    }
    h1[m * 128 + t] = acc;
}

// ---------------------------------------------------------------------------
// GEMM2: h2b = bf16 pre-swizzled "LDS image" of h1 @ w2^T + b2.
// byte(m, n) = (n>>6)*32768 + ((m*128 + ((n&63)>>3)*16) ^ ((m&7)<<4)) + (n&7)*2
// ---------------------------------------------------------------------------
__global__ __launch_bounds__(256) void gemm2_k(const float* __restrict__ h1,
                                               const float* __restrict__ w2,
                                               const float* __restrict__ b2,
                                               char* __restrict__ h2b) {
    __shared__ float As[64][129];
    __shared__ float Bs[64][129];
    const int nb = blockIdx.x, mb = blockIdx.y, t = threadIdx.x;
#pragma unroll
    for (int i = 0; i < 8; ++i) {
        int idx = i * 256 + t;
        int row = idx >> 5, c4 = (idx & 31) * 4;
        float4 a = *(const float4*)(h1 + (mb * 64 + row) * 128 + c4);
        As[row][c4 + 0] = a.x; As[row][c4 + 1] = a.y;
        As[row][c4 + 2] = a.z; As[row][c4 + 3] = a.w;
        float4 bv = *(const float4*)(w2 + (nb * 64 + row) * 128 + c4);
        Bs[row][c4 + 0] = bv.x; Bs[row][c4 + 1] = bv.y;
        Bs[row][c4 + 2] = bv.z; Bs[row][c4 + 3] = bv.w;
    }
    __syncthreads();
    const int tx = t & 15, ty = t >> 4;
    float acc[4][4] = {};
#pragma unroll 4
    for (int k = 0; k < 128; ++k) {
        float a[4], b[4];
#pragma unroll
        for (int i = 0; i < 4; ++i) a[i] = As[ty * 4 + i][k];
#pragma unroll
        for (int j = 0; j < 4; ++j) b[j] = Bs[tx * 4 + j][k];
#pragma unroll
        for (int i = 0; i < 4; ++i)
#pragma unroll
            for (int j = 0; j < 4; ++j) acc[i][j] += a[i] * b[j];
    }
#pragma unroll
    for (int i = 0; i < 4; ++i)
#pragma unroll
        for (int j = 0; j < 4; ++j) {
            int m = mb * 64 + ty * 4 + i;
            int n = nb * 64 + tx * 4 + j;
            float v = acc[i][j] + b2[n];
            int kb = n >> 6, r = n & 63;
            int byte = kb * 32768 + ((m * 128 + (r >> 3) * 16) ^ ((m & 7) << 4)) + (r & 7) * 2;
            *(__bf16*)(h2b + byte) = (__bf16)v;
        }
}

// ---------------------------------------------------------------------------
// GEMM3 v3: async pipeline, ONE barrier per K-step, no vmcnt(0) in the loop.
//   A: global_load_lds 16B from pre-swizzled bf16 image, ring depth 3 (96 KB).
//   W: global fp32 -> regs one tile AHEAD; cvt+ds_write late; dbuf 2x8KB.
// The compiler's own reg-dep s_waitcnt before the W cvt retires W(t+1) and,
// transitively, the OLDER A(t+1) DMAs. Barrier at end of each iter makes
// ring-slot overwrites safe (all waves finished reading slot t-1).
// ---------------------------------------------------------------------------
__global__ __launch_bounds__(512, 1) void gemm3_k(const char* __restrict__ Ab,
                                                  const float* __restrict__ W,
                                                  const float* __restrict__ bias,
                                                  float* __restrict__ C) {
    __shared__ __align__(16) char lds[3 * 32768 + 2 * 8192];
    char* const Wb = lds + 98304;
    const int tid = threadIdx.x;
    const int n0 = blockIdx.x * 64;
    const int lane = tid & 63, wid = tid >> 6;
    const int mrow = tid >> 3, kb8 = tid & 7;

#define ISSUE_A(t, slot)                                                            \
    {                                                                               \
        const char* _s = Ab + (t) * 32768 + wid * 4096 + lane * 16;                 \
        char* _d = lds + (slot) * 32768 + wid * 4096;                               \
        __builtin_amdgcn_global_load_lds((as1_uint*)(_s), (as3_uint*)(_d), 16, 0, 0);             \
        __builtin_amdgcn_global_load_lds((as1_uint*)(_s + 1024), (as3_uint*)(_d + 1024), 16, 0, 0); \
        __builtin_amdgcn_global_load_lds((as1_uint*)(_s + 2048), (as3_uint*)(_d + 2048), 16, 0, 0); \
        __builtin_amdgcn_global_load_lds((as1_uint*)(_s + 3072), (as3_uint*)(_d + 3072), 16, 0, 0); \
    }

    float4 w0r, w1r;
    auto loadW = [&](int t) {
        const float* q = W + (n0 + mrow) * 4096 + t * 64 + kb8 * 8;
        w0r = *(const float4*)q;
        w1r = *(const float4*)(q + 4);
    };
    auto storeW = [&](int buf) {
        bf16x8 p;
        p[0] = (__bf16)w0r.x; p[1] = (__bf16)w0r.y; p[2] = (__bf16)w0r.z; p[3] = (__bf16)w0r.w;
        p[4] = (__bf16)w1r.x; p[5] = (__bf16)w1r.y; p[6] = (__bf16)w1r.z; p[7] = (__bf16)w1r.w;
        *(bf16x8*)(Wb + buf * 8192 + ((mrow * 128 + kb8 * 16) ^ ((mrow & 7) << 4))) = p;
    };

    // ---- prologue: W(0) regs; A(0), A(1) DMA; W(0) -> LDS; wait A(0) only ----
    loadW(0);
    ISSUE_A(0, 0);
    ISSUE_A(1, 1);
    storeW(0);  // compiler waits for w regs here
    asm volatile("s_waitcnt vmcnt(4)" ::: "memory");  // A(0) resident; A(1) in flight
    __builtin_amdgcn_sched_barrier(0);
    asm volatile("s_waitcnt lgkmcnt(0)" ::: "memory");  // Wb(0) landed
    __builtin_amdgcn_sched_barrier(0);
    __builtin_amdgcn_s_barrier();

    const int lr = lane & 15, lq = lane >> 4;
    const int wm = wid >> 1, wn = wid & 1;

    f32x4 acc[4][2];
    const f32x4 zero = {0.f, 0.f, 0.f, 0.f};
#pragma unroll
    for (int mi = 0; mi < 4; ++mi)
#pragma unroll
        for (int ni = 0; ni < 2; ++ni) acc[mi][ni] = zero;

    int sA = 0;   // ring slot of tile t
    int sA2 = 2;  // ring slot of tile t+2
    for (int t = 0; t < 64; ++t) {
        const int cur = t & 1;
        if (t < 63) loadW(t + 1);           // issue W stream (oldest vmem this iter)
        if (t < 62) ISSUE_A(t + 2, sA2);    // A two tiles ahead (newest, never drained)

        const char* Ac = lds + sA * 32768;
        const char* Wc = Wb + cur * 8192;
#pragma unroll
        for (int kk = 0; kk < 2; ++kk) {
            const int kb = kk * 4 + lq;
            bf16x8 af[4], bfv[2];
#pragma unroll
            for (int mi = 0; mi < 4; ++mi) {
                int m = wm * 64 + mi * 16 + lr;
                af[mi] = *(const bf16x8*)(Ac + ((m * 128 + kb * 16) ^ ((m & 7) << 4)));
            }
#pragma unroll
            for (int ni = 0; ni < 2; ++ni) {
                int n = wn * 32 + ni * 16 + lr;
                bfv[ni] = *(const bf16x8*)(Wc + ((n * 128 + kb * 16) ^ ((n & 7) << 4)));
            }
#pragma unroll
            for (int mi = 0; mi < 4; ++mi)
#pragma unroll
                for (int ni = 0; ni < 2; ++ni)
                    acc[mi][ni] = __builtin_amdgcn_mfma_f32_16x16x32_bf16(
                        af[mi], bfv[ni], acc[mi][ni], 0, 0, 0);
        }

        if (t < 63) {
            storeW(cur ^ 1);  // compiler's reg wait retires W(t+1) AND older A(t+1)
            asm volatile("s_waitcnt lgkmcnt(0)" ::: "memory");
            __builtin_amdgcn_sched_barrier(0);
            __builtin_amdgcn_s_barrier();
        }
        sA = (sA == 2) ? 0 : sA + 1;
        sA2 = (sA2 == 2) ? 0 : sA2 + 1;
    }
#undef ISSUE_A

    float bv[2];
#pragma unroll
    for (int ni = 0; ni < 2; ++ni) bv[ni] = bias[n0 + wn * 32 + ni * 16 + lr];
#pragma unroll
    for (int mi = 0; mi < 4; ++mi)
#pragma unroll
        for (int ni = 0; ni < 2; ++ni) {
            const int n = n0 + wn * 32 + ni * 16 + lr;
#pragma unroll
            for (int r = 0; r < 4; ++r) {
                int m = wm * 64 + mi * 16 + lq * 4 + r;
                C[m * 16384 + n] = acc[mi][ni][r] + bv[ni];
            }
        }
}

// ---------------------------------------------------------------------------
// Fused conv x5 (bf16 MFMA) + square + Sinkhorn. One block per batch element.
// ---------------------------------------------------------------------------
template <int CIN, int COUT, int DIL, int MT, int NT>
__device__ __forceinline__ void conv_core(const char* xt, char* wl,
                                          const float* __restrict__ w,
                                          f32x4 (&acc)[MT][NT], int tid) {
    constexpr int RB = CIN * 2;
    const int lane = tid & 63, wid = tid >> 6;
    const int lr = lane & 15, lq = lane >> 4;
    const int cobase = wid * (COUT / 4);
    const f32x4 zero = {0.f, 0.f, 0.f, 0.f};
#pragma unroll
    for (int mi = 0; mi < MT; ++mi)
#pragma unroll
        for (int ni = 0; ni < NT; ++ni) acc[mi][ni] = zero;

    for (int cic = 0; cic < CIN / 32; ++cic) {
        for (int idx = tid; idx < COUT * 4; idx += 256) {
            int co = idx >> 2, cib = idx & 3, ci0 = cic * 32 + cib * 8;
            const float* src = w + co * (CIN * 3) + ci0 * 3;
            float v[24];
#pragma unroll
            for (int u = 0; u < 6; ++u) {
                float4 f = *(const float4*)(src + u * 4);
                v[u * 4 + 0] = f.x; v[u * 4 + 1] = f.y;
                v[u * 4 + 2] = f.z; v[u * 4 + 3] = f.w;
            }
#pragma unroll
            for (int tp = 0; tp < 3; ++tp) {
                bf16x8 pk;
#pragma unroll
                for (int j = 0; j < 8; ++j) pk[j] = (__bf16)v[j * 3 + tp];
                *(bf16x8*)(wl + ((tp * 4 + cib) * COUT + co) * 16) = pk;
            }
        }
        __syncthreads();
#pragma unroll
        for (int tp = 0; tp < 3; ++tp) {
            bf16x8 af[MT];
#pragma unroll
            for (int mi = 0; mi < MT; ++mi)
                af[mi] = *(const bf16x8*)(wl + ((tp * 4 + lq) * COUT + cobase + mi * 16 + lr) * 16);
            bf16x8 bfr[NT];
#pragma unroll
            for (int ni = 0; ni < NT; ++ni) {
                int colX = ni * 16 + lr + tp * DIL;
                bfr[ni] = *(const bf16x8*)(xt + ((colX * RB + (cic * 4 + lq) * 16) ^ ((colX & 7) << 4)));
            }
#pragma unroll
            for (int mi = 0; mi < MT; ++mi)
#pragma unroll
                for (int ni = 0; ni < NT; ++ni)
                    acc[mi][ni] = __builtin_amdgcn_mfma_f32_16x16x32_bf16(
                        af[mi], bfr[ni], acc[mi][ni], 0, 0, 0);
        }
        __syncthreads();
    }
}

template <int COUT, int LOUT, int MT, int NT>
__device__ __forceinline__ void write_xt(char* xt_out, const f32x4 (&acc)[MT][NT],
                                         const float* __restrict__ bias, int tid) {
    constexpr int RBO = COUT * 2;
    const int lane = tid & 63, wid = tid >> 6;
    const int lr = lane & 15, lq = lane >> 4;
    const int cobase = wid * (COUT / 4);
#pragma unroll
    for (int mi = 0; mi < MT; ++mi)
#pragma unroll
        for (int ni = 0; ni < NT; ++ni) {
            int l = ni * 16 + lr;
            if (l < LOUT) {
#pragma unroll
                for (int r = 0; r < 4; ++r) {
                    int co = cobase + mi * 16 + lq * 4 + r;
                    float y = acc[mi][ni][r] + bias[co];
                    int byte = (l * RBO + ((co >> 3) << 4) + (co & 7) * 2) ^ ((l & 7) << 4);
                    *(__bf16*)(xt_out + byte) = (__bf16)y;
                }
            }
        }
}

__global__ __launch_bounds__(256, 1) void convsink_k(
    const float* __restrict__ h3,
    const float* __restrict__ cw1, const float* __restrict__ cb1,
    const float* __restrict__ cw2, const float* __restrict__ cb2,
    const float* __restrict__ cw3, const float* __restrict__ cb3,
    const float* __restrict__ cw4, const float* __restrict__ cb4,
    const float* __restrict__ cw5, const float* __restrict__ cb5,
    float* __restrict__ out) {
    __shared__ __align__(16) char lds[34816 + 31488 + 36864 + 16640];
    char* xtA = lds;
    char* xtB = lds + 34816;
    char* wl = lds + 34816 + 31488;
    float* S = (float*)(lds + 34816 + 31488 + 36864);

    const int b = blockIdx.x, tid = threadIdx.x;
    const float* src = h3 + b * 16384;

#pragma unroll
    for (int i = 0; i < 8; ++i) {
        int idx = i * 256 + tid;
        int l = idx & 127, cib = idx >> 7;
        bf16x8 p;
#pragma unroll
        for (int j = 0; j < 8; ++j) p[j] = (__bf16)src[(cib * 8 + j) * 128 + l];
        *(bf16x8*)(xtA + ((l * 256 + cib * 16) ^ ((l & 7) << 4))) = p;
    }
    __syncthreads();

    {
        f32x4 acc[3][5];
        conv_core<128, 192, 28, 3, 5>(xtA, wl, cw1, acc, tid);
        write_xt<192, 72, 3, 5>(xtB, acc, cb1, tid);
    }
    __syncthreads();
    {
        f32x4 acc[2][5];
        conv_core<192, 128, 1, 2, 5>(xtB, wl, cw2, acc, tid);
        write_xt<128, 70, 2, 5>(xtA, acc, cb2, tid);
    }
    __syncthreads();
    {
        f32x4 acc[1][5];
        conv_core<128, 64, 1, 1, 5>(xtA, wl, cw3, acc, tid);
        write_xt<64, 68, 1, 5>(xtB, acc, cb3, tid);
    }
    __syncthreads();
    {
        f32x4 acc[1][5];
        conv_core<64, 64, 1, 1, 5>(xtB, wl, cw4, acc, tid);
        write_xt<64, 66, 1, 5>(xtA, acc, cb4, tid);
    }
    __syncthreads();
    {
        f32x4 acc[1][4];
        conv_core<64, 64, 1, 1, 4>(xtA, wl, cw5, acc, tid);
        const int lane = tid & 63, wid = tid >> 6;
        const int lr = lane & 15, lq = lane >> 4;
        const int cobase = wid * 16;
#pragma unroll
        for (int ni = 0; ni < 4; ++ni) {
            int l = ni * 16 + lr;
#pragma unroll
            for (int r = 0; r < 4; ++r) {
                int co = cobase + lq * 4 + r;
                float y = acc[0][ni][r] + cb5[co];
                S[co * 65 + l] = y * y + 0.001f;
            }
        }
    }
    __syncthreads();

    const int q = tid & 3, rid = tid >> 2;
    for (int it = 0; it < 10; ++it) {
        float p = 0.f;
#pragma unroll
        for (int j = 0; j < 16; ++j) p += S[rid * 65 + q * 16 + j];
        p += __shfl_xor(p, 1);
        p += __shfl_xor(p, 2);
        float inv = 1.0f / p;
#pragma unroll
        for (int j = 0; j < 16; ++j) S[rid * 65 + q * 16 + j] *= inv;
        __syncthreads();
        float c = 0.f;
#pragma unroll
        for (int i = 0; i < 16; ++i) c += S[(q * 16 + i) * 65 + rid];
        c += __shfl_xor(c, 1);
        c += __shfl_xor(c, 2);
        float invc = 1.0f / c;
#pragma unroll
        for (int i = 0; i < 16; ++i) S[(q * 16 + i) * 65 + rid] *= invc;
        __syncthreads();
    }

#pragma unroll
    for (int i = 0; i < 16; ++i) {
        int idx = i * 256 + tid;
        out[b * 4096 + idx] = S[(idx >> 6) * 65 + (idx & 63)];
    }
}

// ---------------------------------------------------------------------------
extern "C" void kernel_launch(void* const* d_in, const int* in_sizes, int n_in,
                              void* d_out, int out_size, void* d_ws, size_t ws_size,
                              hipStream_t stream) {
    const float* x = (const float*)d_in[0];
    const float* w1 = (const float*)d_in[1];
    const float* b1 = (const float*)d_in[2];
    const float* w2 = (const float*)d_in[3];
    const float* b2 = (const float*)d_in[4];
    const float* w3 = (const float*)d_in[5];
    const float* b3 = (const float*)d_in[6];
    const float* cw1 = (const float*)d_in[7];
    const float* cb1 = (const float*)d_in[8];
    const float* cw2 = (const float*)d_in[9];
    const float* cb2 = (const float*)d_in[10];
    const float* cw3 = (const float*)d_in[11];
    const float* cb3 = (const float*)d_in[12];
    const float* cw4 = (const float*)d_in[13];
    const float* cb4 = (const float*)d_in[14];
    const float* cw5 = (const float*)d_in[15];
    const float* cb5 = (const float*)d_in[16];
    float* out = (float*)d_out;

    char* ws = (char*)d_ws;
    float* h1 = (float*)(ws);                       // 131072 B
    char* h2b = ws + 131072;                        // 2 MB bf16 image
    float* h3 = (float*)(ws + 131072 + 2097152);    // 16777216 B

    gemm1_k<<<256, 128, 0, stream>>>(x, w1, b1, h1);
    gemm2_k<<<dim3(64, 4), 256, 0, stream>>>(h1, w2, b2, h2b);
    gemm3_k<<<256, 512, 0, stream>>>(h2b, w3, b3, h3);
    convsink_k<<<256, 256, 0, stream>>>(h3, cw1, cb1, cw2, cb2, cw3, cb3,
                                        cw4, cb4, cw5, cb5, out);
}